// Round 1
// baseline (7147.168 us; speedup 1.0000x reference)
//
#include <hip/hip_runtime.h>
#include <hip/hip_bf16.h>

// Problem constants (fixed by the reference)
#define V  32000
#define D  512
#define H  512
#define B  32
#define T  128
#define L  48      // max_len
#define KLIN 1024  // D? no: 2H for lin, D+H for gru input part
#define KGRU 1536  // (D+H) + H

typedef __attribute__((ext_vector_type(8))) short bf16x8;
typedef __attribute__((ext_vector_type(4))) float f32x4;

// ---------- f32 -> (bf16 hi, bf16 lo) split, RNE ----------
__device__ __forceinline__ void split1(float f, unsigned short* hi, unsigned short* lo) {
    unsigned u  = __float_as_uint(f);
    unsigned uh = u + (0x7FFFu + ((u >> 16) & 1u));
    unsigned short hs = (unsigned short)(uh >> 16);
    float hf = __uint_as_float(((unsigned)hs) << 16);
    float l  = f - hf;                       // exact (Sterbenz)
    unsigned ul = __float_as_uint(l);
    ul += 0x7FFFu + ((ul >> 16) & 1u);
    *hi = hs;
    *lo = (unsigned short)(ul >> 16);
}

__device__ __forceinline__ void split8(const float* __restrict__ p, bf16x8& hi, bf16x8& lo) {
    float4 w0 = reinterpret_cast<const float4*>(p)[0];
    float4 w1 = reinterpret_cast<const float4*>(p)[1];
    float w[8] = {w0.x, w0.y, w0.z, w0.w, w1.x, w1.y, w1.z, w1.w};
    #pragma unroll
    for (int i = 0; i < 8; ++i) {
        unsigned u  = __float_as_uint(w[i]);
        unsigned uh = u + (0x7FFFu + ((u >> 16) & 1u));
        unsigned short hs = (unsigned short)(uh >> 16);
        float hf = __uint_as_float(((unsigned)hs) << 16);
        float l  = w[i] - hf;
        unsigned ul = __float_as_uint(l);
        ul += 0x7FFFu + ((ul >> 16) & 1u);
        hi[i] = (short)hs;
        lo[i] = (short)(ul >> 16);
    }
}

// ---------- init: e0 = emb[inputs], ctx0 = context, h0 = 0 ----------
__global__ void init_state(const int* __restrict__ inputs, const float* __restrict__ context,
                           const float* __restrict__ emb,
                           float* __restrict__ h,
                           unsigned short* __restrict__ Xghi, unsigned short* __restrict__ Xglo,
                           unsigned short* __restrict__ Xlhi, unsigned short* __restrict__ Xllo)
{
    int idx = blockIdx.x * 256 + threadIdx.x;   // 0..B*H-1
    int b = idx >> 9, j = idx & 511;
    int tok = inputs[b];
    float e = emb[(size_t)tok * D + j];
    split1(e, &Xghi[b * KGRU + j], &Xglo[b * KGRU + j]);
    float c = context[b * H + j];
    split1(c, &Xghi[b * KGRU + 512 + j], &Xglo[b * KGRU + 512 + j]);
    split1(c, &Xlhi[b * KLIN + 512 + j], &Xllo[b * KLIN + 512 + j]);
    Xghi[b * KGRU + 1024 + j] = 0;
    Xglo[b * KGRU + 1024 + j] = 0;
    h[b * H + j] = 0.f;
}

// ---------- energies = enc @ attn_W^T + attn_b  (4096x512, K=512), 3-pass split-bf16 ----------
__global__ void __launch_bounds__(256) energies_gemm(
    const float* __restrict__ enc, const float* __restrict__ attnW,
    const float* __restrict__ attnb, float* __restrict__ energies)
{
    int wave = threadIdx.x >> 6, lane = threadIdx.x & 63;
    int col = blockIdx.y * 64 + wave * 16 + (lane & 15);
    int kg  = (lane >> 4) * 8;
    int arow0 = blockIdx.x * 32 + (lane & 15);
    f32x4 acc0 = {0.f,0.f,0.f,0.f}, acc1 = {0.f,0.f,0.f,0.f};
    for (int k0 = 0; k0 < 512; k0 += 32) {
        bf16x8 bh, bl;  split8(attnW + (size_t)col * 512 + k0 + kg, bh, bl);
        bf16x8 a0h, a0l; split8(enc + (size_t)arow0 * 512 + k0 + kg, a0h, a0l);
        bf16x8 a1h, a1l; split8(enc + (size_t)(arow0 + 16) * 512 + k0 + kg, a1h, a1l);
        acc0 = __builtin_amdgcn_mfma_f32_16x16x32_bf16(a0h, bh, acc0, 0, 0, 0);
        acc1 = __builtin_amdgcn_mfma_f32_16x16x32_bf16(a1h, bh, acc1, 0, 0, 0);
        acc0 = __builtin_amdgcn_mfma_f32_16x16x32_bf16(a0l, bh, acc0, 0, 0, 0);
        acc1 = __builtin_amdgcn_mfma_f32_16x16x32_bf16(a1l, bh, acc1, 0, 0, 0);
        acc0 = __builtin_amdgcn_mfma_f32_16x16x32_bf16(a0h, bl, acc0, 0, 0, 0);
        acc1 = __builtin_amdgcn_mfma_f32_16x16x32_bf16(a1h, bl, acc1, 0, 0, 0);
    }
    float bias = attnb[col];
    int r0 = (lane >> 4) * 4;
    #pragma unroll
    for (int i = 0; i < 4; ++i) {
        int row = blockIdx.x * 32 + r0 + i;
        energies[(size_t)row * 512 + col]        = acc0[i] + bias;
        energies[(size_t)(row + 16) * 512 + col] = acc1[i] + bias;
    }
}

// ---------- GRU gate GEMM: partials of gi (k 0..1023) and gh (k 1024..1535) ----------
// parts[ks][b][j], ks 0/1 -> gi halves, ks 2/3 -> gh halves
__global__ void __launch_bounds__(256) gate_gemm(
    const float* __restrict__ Wih, const float* __restrict__ Whh,
    const unsigned short* __restrict__ Xghi, const unsigned short* __restrict__ Xglo,
    float* __restrict__ parts)
{
    int ks = blockIdx.y;
    int kbeg = (ks < 2) ? ks * 512 : 1024 + (ks - 2) * 256;
    int kend = kbeg + ((ks < 2) ? 512 : 256);
    int wave = threadIdx.x >> 6, lane = threadIdx.x & 63;
    int col = blockIdx.x * 64 + wave * 16 + (lane & 15);   // gate index j in [0,1536)
    int kg  = (lane >> 4) * 8;
    const unsigned short* x0h = Xghi + (lane & 15) * KGRU + kg;
    const unsigned short* x0l = Xglo + (lane & 15) * KGRU + kg;
    f32x4 acc0 = {0.f,0.f,0.f,0.f}, acc1 = {0.f,0.f,0.f,0.f};
    for (int k0 = kbeg; k0 < kend; k0 += 32) {
        const float* src = (k0 < 1024) ? (Wih + (size_t)col * 1024 + k0 + kg)
                                       : (Whh + (size_t)col * 512 + (k0 - 1024) + kg);
        bf16x8 bh, bl;  split8(src, bh, bl);
        bf16x8 a0h = *(const bf16x8*)(x0h + k0);
        bf16x8 a0l = *(const bf16x8*)(x0l + k0);
        bf16x8 a1h = *(const bf16x8*)(x0h + 16 * KGRU + k0);
        bf16x8 a1l = *(const bf16x8*)(x0l + 16 * KGRU + k0);
        acc0 = __builtin_amdgcn_mfma_f32_16x16x32_bf16(a0h, bh, acc0, 0, 0, 0);
        acc1 = __builtin_amdgcn_mfma_f32_16x16x32_bf16(a1h, bh, acc1, 0, 0, 0);
        acc0 = __builtin_amdgcn_mfma_f32_16x16x32_bf16(a0l, bh, acc0, 0, 0, 0);
        acc1 = __builtin_amdgcn_mfma_f32_16x16x32_bf16(a1l, bh, acc1, 0, 0, 0);
        acc0 = __builtin_amdgcn_mfma_f32_16x16x32_bf16(a0h, bl, acc0, 0, 0, 0);
        acc1 = __builtin_amdgcn_mfma_f32_16x16x32_bf16(a1h, bl, acc1, 0, 0, 0);
    }
    int r0 = (lane >> 4) * 4;
    #pragma unroll
    for (int i = 0; i < 4; ++i) {
        parts[((size_t)ks * 32 + r0 + i) * KGRU + col]      = acc0[i];
        parts[((size_t)ks * 32 + r0 + i + 16) * KGRU + col] = acc1[i];
    }
}

// ---------- GRU combine: gates -> h (in place), write X fragments ----------
__global__ void gru_combine(const float* __restrict__ parts,
                            const float* __restrict__ bih, const float* __restrict__ bhh,
                            float* __restrict__ h,
                            unsigned short* __restrict__ Xlhi, unsigned short* __restrict__ Xllo,
                            unsigned short* __restrict__ Xghi, unsigned short* __restrict__ Xglo)
{
    int idx = blockIdx.x * 256 + threadIdx.x;  // 0..B*H-1
    int b = idx >> 9, j = idx & 511;
    const float* p0 = parts;
    const float* p1 = parts + (size_t)32 * KGRU;
    const float* p2 = parts + (size_t)64 * KGRU;
    const float* p3 = parts + (size_t)96 * KGRU;
    size_t base = (size_t)b * KGRU;
    float gi_r = p0[base + j]        + p1[base + j]        + bih[j];
    float gi_z = p0[base + 512 + j]  + p1[base + 512 + j]  + bih[512 + j];
    float gi_n = p0[base + 1024 + j] + p1[base + 1024 + j] + bih[1024 + j];
    float gh_r = p2[base + j]        + p3[base + j]        + bhh[j];
    float gh_z = p2[base + 512 + j]  + p3[base + 512 + j]  + bhh[512 + j];
    float gh_n = p2[base + 1024 + j] + p3[base + 1024 + j] + bhh[1024 + j];
    float r = 1.f / (1.f + expf(-(gi_r + gh_r)));
    float z = 1.f / (1.f + expf(-(gi_z + gh_z)));
    float n = tanhf(gi_n + r * gh_n);
    float hn = (1.f - z) * n + z * h[b * H + j];
    h[b * H + j] = hn;
    split1(hn, &Xlhi[b * KLIN + j], &Xllo[b * KLIN + j]);          // X_lin h-half (this step)
    split1(hn, &Xghi[b * KGRU + 1024 + j], &Xglo[b * KGRU + 1024 + j]); // X_gru h-part (next step)
}

// ---------- score GEMM: out[b*48+t][:] = [h,ctx] @ lin_W^T + lin_b (raw scores) ----------
__global__ void __launch_bounds__(256) score_gemm(
    const float* __restrict__ linW, const float* __restrict__ linb,
    const unsigned short* __restrict__ Xlhi, const unsigned short* __restrict__ Xllo,
    float* __restrict__ out, int t)
{
    int wave = threadIdx.x >> 6, lane = threadIdx.x & 63;
    int col = blockIdx.x * 64 + wave * 16 + (lane & 15);
    int kg  = (lane >> 4) * 8;
    const float* wp = linW + (size_t)col * 1024 + kg;
    const unsigned short* x0h = Xlhi + (lane & 15) * KLIN + kg;
    const unsigned short* x0l = Xllo + (lane & 15) * KLIN + kg;
    f32x4 acc0 = {0.f,0.f,0.f,0.f}, acc1 = {0.f,0.f,0.f,0.f};
    #pragma unroll 2
    for (int k0 = 0; k0 < 1024; k0 += 32) {
        bf16x8 bh, bl;  split8(wp + k0, bh, bl);
        bf16x8 a0h = *(const bf16x8*)(x0h + k0);
        bf16x8 a0l = *(const bf16x8*)(x0l + k0);
        bf16x8 a1h = *(const bf16x8*)(x0h + 16 * KLIN + k0);
        bf16x8 a1l = *(const bf16x8*)(x0l + 16 * KLIN + k0);
        acc0 = __builtin_amdgcn_mfma_f32_16x16x32_bf16(a0h, bh, acc0, 0, 0, 0);
        acc1 = __builtin_amdgcn_mfma_f32_16x16x32_bf16(a1h, bh, acc1, 0, 0, 0);
        acc0 = __builtin_amdgcn_mfma_f32_16x16x32_bf16(a0l, bh, acc0, 0, 0, 0);
        acc1 = __builtin_amdgcn_mfma_f32_16x16x32_bf16(a1l, bh, acc1, 0, 0, 0);
        acc0 = __builtin_amdgcn_mfma_f32_16x16x32_bf16(a0h, bl, acc0, 0, 0, 0);
        acc1 = __builtin_amdgcn_mfma_f32_16x16x32_bf16(a1h, bl, acc1, 0, 0, 0);
    }
    float bias = linb[col];
    int r0 = (lane >> 4) * 4;
    #pragma unroll
    for (int i = 0; i < 4; ++i) {
        int b0 = r0 + i;
        out[(size_t)(b0 * L + t) * V + col]        = acc0[i] + bias;
        out[(size_t)((b0 + 16) * L + t) * V + col] = acc1[i] + bias;
    }
}

// ---------- reduce (lse/argmax/logp) + attention (alpha, ctx) : one block per batch ----------
__global__ void __launch_bounds__(256) reduce_attn(
    float* __restrict__ out, const float* __restrict__ emb,
    const float* __restrict__ energies, const float* __restrict__ enc,
    const float* __restrict__ h,
    unsigned short* __restrict__ Xghi, unsigned short* __restrict__ Xglo,
    unsigned short* __restrict__ Xlhi, unsigned short* __restrict__ Xllo, int t)
{
    __shared__ float red[256];
    __shared__ int   redi[256];
    __shared__ float aw[128];
    __shared__ float hrow[512];
    int b = blockIdx.x, tid = threadIdx.x;
    float* row = out + (size_t)(b * L + t) * V;

    // phase 1: max + argmax (tie -> lowest index)
    float m = -INFINITY; int mi = 0x7fffffff;
    for (int v = tid; v < V; v += 256) {
        float s = row[v];
        if (s > m) { m = s; mi = v; }
    }
    red[tid] = m; redi[tid] = mi; __syncthreads();
    for (int s = 128; s > 0; s >>= 1) {
        if (tid < s) {
            float ov = red[tid + s]; int oi = redi[tid + s];
            if (ov > red[tid] || (ov == red[tid] && oi < redi[tid])) { red[tid] = ov; redi[tid] = oi; }
        }
        __syncthreads();
    }
    float M = red[0]; int amax = redi[0];
    __syncthreads();

    // phase 2: sum exp
    float se = 0.f;
    for (int v = tid; v < V; v += 256) se += expf(row[v] - M);
    red[tid] = se; __syncthreads();
    for (int s = 128; s > 0; s >>= 1) { if (tid < s) red[tid] += red[tid + s]; __syncthreads(); }
    float lse = M + logf(red[0]);
    __syncthreads();

    // phase 3: logp = score - lse (in place, still cache-hot)
    for (int v = tid; v < V; v += 256) row[v] -= lse;

    // phase 4: e_next = emb[argmax] -> X_gru e-part (next step)
    for (int j = tid; j < 512; j += 256)
        split1(emb[(size_t)amax * D + j], &Xghi[b * KGRU + j], &Xglo[b * KGRU + j]);

    // phase 5: attention logits over T, softmax, ctx
    for (int j = tid; j < 512; j += 256) hrow[j] = h[b * H + j];
    __syncthreads();
    {
        int tt = tid >> 1, half = tid & 1;
        const float4* e4 = (const float4*)(energies + ((size_t)(b * T + tt)) * 512 + half * 256);
        const float4* h4 = (const float4*)(hrow + half * 256);
        float p = 0.f;
        #pragma unroll 4
        for (int k = 0; k < 64; ++k) {
            float4 a = e4[k], c = h4[k];
            p += a.x * c.x + a.y * c.y + a.z * c.z + a.w * c.w;
        }
        p += __shfl_xor(p, 1);
        if (half == 0) aw[tt] = p;
    }
    __syncthreads();
    // softmax over 128
    red[tid] = (tid < 128) ? aw[tid] : -INFINITY; __syncthreads();
    for (int s = 128; s > 0; s >>= 1) { if (tid < s) red[tid] = fmaxf(red[tid], red[tid + s]); __syncthreads(); }
    float am = red[0];
    __syncthreads();
    if (tid < 128) { float e = expf(aw[tid] - am); aw[tid] = e; red[tid] = e; } else red[tid] = 0.f;
    __syncthreads();
    for (int s = 128; s > 0; s >>= 1) { if (tid < s) red[tid] += red[tid + s]; __syncthreads(); }
    float asum = red[0];
    __syncthreads();
    // ctx[j] = sum_tt alpha*enc ; each thread owns cols tid and tid+256
    float c0 = 0.f, c1 = 0.f;
    for (int tt2 = 0; tt2 < T; ++tt2) {
        float a = aw[tt2];
        const float* er = enc + ((size_t)(b * T + tt2)) * 512;
        c0 += a * er[tid];
        c1 += a * er[tid + 256];
    }
    c0 /= asum; c1 /= asum;
    split1(c0, &Xlhi[b * KLIN + 512 + tid],       &Xllo[b * KLIN + 512 + tid]);
    split1(c1, &Xlhi[b * KLIN + 512 + tid + 256], &Xllo[b * KLIN + 512 + tid + 256]);
    split1(c0, &Xghi[b * KGRU + 512 + tid],       &Xglo[b * KGRU + 512 + tid]);
    split1(c1, &Xghi[b * KGRU + 512 + tid + 256], &Xglo[b * KGRU + 512 + tid + 256]);
}

extern "C" void kernel_launch(void* const* d_in, const int* in_sizes, int n_in,
                              void* d_out, int out_size, void* d_ws, size_t ws_size,
                              hipStream_t stream) {
    const int*   inputs  = (const int*)d_in[0];
    const float* context = (const float*)d_in[1];
    // d_in[2] = max_len (constant 48, hardcoded)
    const float* enc     = (const float*)d_in[3];
    const float* emb     = (const float*)d_in[4];
    const float* Wih     = (const float*)d_in[5];
    const float* Whh     = (const float*)d_in[6];
    const float* bih     = (const float*)d_in[7];
    const float* bhh     = (const float*)d_in[8];
    const float* linW    = (const float*)d_in[9];
    const float* linb    = (const float*)d_in[10];
    const float* attnW   = (const float*)d_in[11];
    const float* attnb   = (const float*)d_in[12];
    float* out = (float*)d_out;

    // workspace layout (all 16B-aligned)
    char* w = (char*)d_ws;
    float* energies = (float*)w;            w += (size_t)B * T * 512 * 4;   // 8.39 MB
    float* parts    = (float*)w;            w += (size_t)4 * 32 * KGRU * 4; // 768 KB
    float* h        = (float*)w;            w += (size_t)B * H * 4;         // 64 KB
    unsigned short* Xghi = (unsigned short*)w; w += (size_t)B * KGRU * 2;   // 96 KB
    unsigned short* Xglo = (unsigned short*)w; w += (size_t)B * KGRU * 2;
    unsigned short* Xlhi = (unsigned short*)w; w += (size_t)B * KLIN * 2;   // 64 KB
    unsigned short* Xllo = (unsigned short*)w; w += (size_t)B * KLIN * 2;

    init_state<<<64, 256, 0, stream>>>(inputs, context, emb, h, Xghi, Xglo, Xlhi, Xllo);
    energies_gemm<<<dim3(128, 8), 256, 0, stream>>>(enc, attnW, attnb, energies);

    for (int t = 0; t < L; ++t) {
        gate_gemm<<<dim3(24, 4), 256, 0, stream>>>(Wih, Whh, Xghi, Xglo, parts);
        gru_combine<<<64, 256, 0, stream>>>(parts, bih, bhh, h, Xlhi, Xllo, Xghi, Xglo);
        score_gemm<<<500, 256, 0, stream>>>(linW, linb, Xlhi, Xllo, out, t);
        reduce_attn<<<32, 256, 0, stream>>>(out, emb, energies, enc, h, Xghi, Xglo, Xlhi, Xllo, t);
    }
}

// Round 2
// 4637.250 us; speedup vs baseline: 1.5413x; 1.5413x over previous
//
#include <hip/hip_runtime.h>
#include <hip/hip_bf16.h>

#define V  32000
#define D  512
#define H  512
#define B  32
#define T  128
#define L  48
#define KLIN 1024
#define KGRU 1536

typedef __attribute__((ext_vector_type(8))) short bf16x8;
typedef __attribute__((ext_vector_type(4))) float f32x4;

// ---------- f32 -> (bf16 hi, bf16 lo) split, RNE ----------
__device__ __forceinline__ void split1(float f, unsigned short* hi, unsigned short* lo) {
    unsigned u  = __float_as_uint(f);
    unsigned uh = u + (0x7FFFu + ((u >> 16) & 1u));
    unsigned short hs = (unsigned short)(uh >> 16);
    float hf = __uint_as_float(((unsigned)hs) << 16);
    float l  = f - hf;
    unsigned ul = __float_as_uint(l);
    ul += 0x7FFFu + ((ul >> 16) & 1u);
    *hi = hs;
    *lo = (unsigned short)(ul >> 16);
}

__device__ __forceinline__ void split8(const float* __restrict__ p, bf16x8& hi, bf16x8& lo) {
    float4 w0 = reinterpret_cast<const float4*>(p)[0];
    float4 w1 = reinterpret_cast<const float4*>(p)[1];
    float w[8] = {w0.x, w0.y, w0.z, w0.w, w1.x, w1.y, w1.z, w1.w};
    #pragma unroll
    for (int i = 0; i < 8; ++i) {
        unsigned u  = __float_as_uint(w[i]);
        unsigned uh = u + (0x7FFFu + ((u >> 16) & 1u));
        unsigned short hs = (unsigned short)(uh >> 16);
        float hf = __uint_as_float(((unsigned)hs) << 16);
        float l  = w[i] - hf;
        unsigned ul = __float_as_uint(l);
        ul += 0x7FFFu + ((ul >> 16) & 1u);
        hi[i] = (short)hs;
        lo[i] = (short)(ul >> 16);
    }
}

// ---------- one-time: split lin_W (row-major, coalesced both sides) ----------
__global__ void presplit_lin(const float* __restrict__ src,
                             unsigned short* __restrict__ hi, unsigned short* __restrict__ lo)
{
    long i = (long)blockIdx.x * 256 + threadIdx.x;     // 8-elem chunk index
    if (i >= (long)V * KLIN / 8) return;
    bf16x8 h8, l8;
    split8(src + i * 8, h8, l8);
    *(bf16x8*)(hi + i * 8) = h8;
    *(bf16x8*)(lo + i * 8) = l8;
}

// ---------- one-time: split gru weights into combined [1536][1536] K-layout ----------
__global__ void presplit_gru(const float* __restrict__ Wih, const float* __restrict__ Whh,
                             unsigned short* __restrict__ hi, unsigned short* __restrict__ lo)
{
    int i = blockIdx.x * 256 + threadIdx.x;            // 8-elem chunk index
    if (i >= 1536 * 192) return;
    int col = i / 192, k = (i % 192) * 8;
    const float* src = (k < 1024) ? (Wih + (size_t)col * 1024 + k)
                                  : (Whh + (size_t)col * 512 + (k - 1024));
    bf16x8 h8, l8;
    split8(src, h8, l8);
    *(bf16x8*)(hi + (size_t)col * KGRU + k) = h8;
    *(bf16x8*)(lo + (size_t)col * KGRU + k) = l8;
}

// ---------- init: e0, ctx0 into Xg[0]/Xl[0], h=0 (h stored transposed [j][b]) ----------
__global__ void init_state(const int* __restrict__ inputs, const float* __restrict__ context,
                           const float* __restrict__ emb, float* __restrict__ h_t,
                           unsigned short* __restrict__ Xghi, unsigned short* __restrict__ Xglo,
                           unsigned short* __restrict__ Xlhi, unsigned short* __restrict__ Xllo)
{
    int idx = blockIdx.x * 256 + threadIdx.x;   // 0..B*H-1
    int b = idx >> 9, j = idx & 511;
    int tok = inputs[b];
    float e = emb[(size_t)tok * D + j];
    split1(e, &Xghi[b * KGRU + j], &Xglo[b * KGRU + j]);
    float c = context[b * H + j];
    split1(c, &Xghi[b * KGRU + 512 + j], &Xglo[b * KGRU + 512 + j]);
    split1(c, &Xlhi[b * KLIN + 512 + j], &Xllo[b * KLIN + 512 + j]);
    Xghi[b * KGRU + 1024 + j] = 0;
    Xglo[b * KGRU + 1024 + j] = 0;
    h_t[j * 32 + b] = 0.f;
}

// ---------- energies = enc @ attn_W^T + attn_b (once) ----------
__global__ void __launch_bounds__(256) energies_gemm(
    const float* __restrict__ enc, const float* __restrict__ attnW,
    const float* __restrict__ attnb, float* __restrict__ energies)
{
    int wave = threadIdx.x >> 6, lane = threadIdx.x & 63;
    int col = blockIdx.y * 64 + wave * 16 + (lane & 15);
    int kg  = (lane >> 4) * 8;
    int arow0 = blockIdx.x * 32 + (lane & 15);
    f32x4 acc0 = {0.f,0.f,0.f,0.f}, acc1 = {0.f,0.f,0.f,0.f};
    for (int k0 = 0; k0 < 512; k0 += 32) {
        bf16x8 bh, bl;  split8(attnW + (size_t)col * 512 + k0 + kg, bh, bl);
        bf16x8 a0h, a0l; split8(enc + (size_t)arow0 * 512 + k0 + kg, a0h, a0l);
        bf16x8 a1h, a1l; split8(enc + (size_t)(arow0 + 16) * 512 + k0 + kg, a1h, a1l);
        acc0 = __builtin_amdgcn_mfma_f32_16x16x32_bf16(a0h, bh, acc0, 0, 0, 0);
        acc1 = __builtin_amdgcn_mfma_f32_16x16x32_bf16(a1h, bh, acc1, 0, 0, 0);
        acc0 = __builtin_amdgcn_mfma_f32_16x16x32_bf16(a0l, bh, acc0, 0, 0, 0);
        acc1 = __builtin_amdgcn_mfma_f32_16x16x32_bf16(a1l, bh, acc1, 0, 0, 0);
        acc0 = __builtin_amdgcn_mfma_f32_16x16x32_bf16(a0h, bl, acc0, 0, 0, 0);
        acc1 = __builtin_amdgcn_mfma_f32_16x16x32_bf16(a1h, bl, acc1, 0, 0, 0);
    }
    float bias = attnb[col];
    int r0 = (lane >> 4) * 4;
    #pragma unroll
    for (int i = 0; i < 4; ++i) {
        int row = blockIdx.x * 32 + r0 + i;
        energies[(size_t)row * 512 + col]        = acc0[i] + bias;
        energies[(size_t)(row + 16) * 512 + col] = acc1[i] + bias;
    }
}

// ---------- fused GRU: gate GEMM + nonlinearity + h update + X writes ----------
// 32 blocks x 384 threads (6 waves): wave w: gate g = w%3, K-half = w/3.
__global__ void __launch_bounds__(384) gru_fused(
    const unsigned short* __restrict__ Ghi, const unsigned short* __restrict__ Glo,
    const unsigned short* __restrict__ Xghi_r, const unsigned short* __restrict__ Xglo_r,
    unsigned short* __restrict__ Xghi_w, unsigned short* __restrict__ Xglo_w,
    unsigned short* __restrict__ Xlhi_w, unsigned short* __restrict__ Xllo_w,
    const float* __restrict__ bih, const float* __restrict__ bhh,
    float* __restrict__ h_t)
{
    __shared__ float AI[3][32][16], AH[3][32][16];
    __shared__ float R[32][16], Z[32][16];
    int w = threadIdx.x >> 6, lane = threadIdx.x & 63;
    int g = (w < 3) ? w : w - 3;
    int half = (w >= 3) ? 1 : 0;
    int c = lane & 15, grp = lane >> 4, kg = grp * 8;
    int j = blockIdx.x * 16 + c;            // h col
    int gcol = g * 512 + j;                 // gate col
    const unsigned short* wh = Ghi + (size_t)gcol * KGRU;
    const unsigned short* wl = Glo + (size_t)gcol * KGRU;
    const unsigned short* xh = Xghi_r + (size_t)c * KGRU;
    const unsigned short* xl = Xglo_r + (size_t)c * KGRU;
    f32x4 aI0 = {0.f,0.f,0.f,0.f}, aI1 = {0.f,0.f,0.f,0.f};
    f32x4 aH0 = {0.f,0.f,0.f,0.f}, aH1 = {0.f,0.f,0.f,0.f};
    for (int k0 = half * 512; k0 < half * 512 + 512; k0 += 32) {
        bf16x8 bh = *(const bf16x8*)(wh + k0 + kg);
        bf16x8 bl = *(const bf16x8*)(wl + k0 + kg);
        bf16x8 a0h = *(const bf16x8*)(xh + k0 + kg);
        bf16x8 a0l = *(const bf16x8*)(xl + k0 + kg);
        bf16x8 a1h = *(const bf16x8*)(xh + 16 * KGRU + k0 + kg);
        bf16x8 a1l = *(const bf16x8*)(xl + 16 * KGRU + k0 + kg);
        aI0 = __builtin_amdgcn_mfma_f32_16x16x32_bf16(a0h, bh, aI0, 0, 0, 0);
        aI1 = __builtin_amdgcn_mfma_f32_16x16x32_bf16(a1h, bh, aI1, 0, 0, 0);
        aI0 = __builtin_amdgcn_mfma_f32_16x16x32_bf16(a0l, bh, aI0, 0, 0, 0);
        aI1 = __builtin_amdgcn_mfma_f32_16x16x32_bf16(a1l, bh, aI1, 0, 0, 0);
        aI0 = __builtin_amdgcn_mfma_f32_16x16x32_bf16(a0h, bl, aI0, 0, 0, 0);
        aI1 = __builtin_amdgcn_mfma_f32_16x16x32_bf16(a1h, bl, aI1, 0, 0, 0);
    }
    for (int k0 = 1024 + half * 256; k0 < 1024 + half * 256 + 256; k0 += 32) {
        bf16x8 bh = *(const bf16x8*)(wh + k0 + kg);
        bf16x8 bl = *(const bf16x8*)(wl + k0 + kg);
        bf16x8 a0h = *(const bf16x8*)(xh + k0 + kg);
        bf16x8 a0l = *(const bf16x8*)(xl + k0 + kg);
        bf16x8 a1h = *(const bf16x8*)(xh + 16 * KGRU + k0 + kg);
        bf16x8 a1l = *(const bf16x8*)(xl + 16 * KGRU + k0 + kg);
        aH0 = __builtin_amdgcn_mfma_f32_16x16x32_bf16(a0h, bh, aH0, 0, 0, 0);
        aH1 = __builtin_amdgcn_mfma_f32_16x16x32_bf16(a1h, bh, aH1, 0, 0, 0);
        aH0 = __builtin_amdgcn_mfma_f32_16x16x32_bf16(a0l, bh, aH0, 0, 0, 0);
        aH1 = __builtin_amdgcn_mfma_f32_16x16x32_bf16(a1l, bh, aH1, 0, 0, 0);
        aH0 = __builtin_amdgcn_mfma_f32_16x16x32_bf16(a0h, bl, aH0, 0, 0, 0);
        aH1 = __builtin_amdgcn_mfma_f32_16x16x32_bf16(a1h, bl, aH1, 0, 0, 0);
    }
    if (w >= 3) {
        #pragma unroll
        for (int i = 0; i < 4; ++i) {
            AI[g][grp * 4 + i][c] = aI0[i];  AI[g][grp * 4 + i + 16][c] = aI1[i];
            AH[g][grp * 4 + i][c] = aH0[i];  AH[g][grp * 4 + i + 16][c] = aH1[i];
        }
    }
    __syncthreads();
    float gi[8], gh[8];
    if (w < 3) {
        float bi = bih[gcol], bhv = bhh[gcol];
        #pragma unroll
        for (int i = 0; i < 4; ++i) {
            gi[i]     = aI0[i] + AI[g][grp * 4 + i][c]      + bi;
            gi[i + 4] = aI1[i] + AI[g][grp * 4 + i + 16][c] + bi;
            gh[i]     = aH0[i] + AH[g][grp * 4 + i][c]      + bhv;
            gh[i + 4] = aH1[i] + AH[g][grp * 4 + i + 16][c] + bhv;
        }
        if (w == 0) {
            #pragma unroll
            for (int i = 0; i < 8; ++i) {
                int b = (i < 4) ? grp * 4 + i : grp * 4 + (i - 4) + 16;
                R[b][c] = 1.f / (1.f + expf(-(gi[i] + gh[i])));
            }
        } else if (w == 1) {
            #pragma unroll
            for (int i = 0; i < 8; ++i) {
                int b = (i < 4) ? grp * 4 + i : grp * 4 + (i - 4) + 16;
                Z[b][c] = 1.f / (1.f + expf(-(gi[i] + gh[i])));
            }
        }
    }
    __syncthreads();
    if (w == 2) {
        float4 h0 = *(const float4*)(h_t + (size_t)j * 32 + grp * 4);
        float4 h1 = *(const float4*)(h_t + (size_t)j * 32 + grp * 4 + 16);
        float hold[8] = {h0.x, h0.y, h0.z, h0.w, h1.x, h1.y, h1.z, h1.w};
        float hn[8];
        #pragma unroll
        for (int i = 0; i < 8; ++i) {
            int b = (i < 4) ? grp * 4 + i : grp * 4 + (i - 4) + 16;
            float n = tanhf(gi[i] + R[b][c] * gh[i]);
            float z = Z[b][c];
            hn[i] = (1.f - z) * n + z * hold[i];
        }
        *(float4*)(h_t + (size_t)j * 32 + grp * 4)      = make_float4(hn[0], hn[1], hn[2], hn[3]);
        *(float4*)(h_t + (size_t)j * 32 + grp * 4 + 16) = make_float4(hn[4], hn[5], hn[6], hn[7]);
        #pragma unroll
        for (int i = 0; i < 8; ++i) {
            int b = (i < 4) ? grp * 4 + i : grp * 4 + (i - 4) + 16;
            split1(hn[i], &Xlhi_w[(size_t)b * KLIN + j], &Xllo_w[(size_t)b * KLIN + j]);
            split1(hn[i], &Xghi_w[(size_t)b * KGRU + 1024 + j], &Xglo_w[(size_t)b * KGRU + 1024 + j]);
        }
    }
}

// ---------- score GEMM (blocks 0..499) + attention/ctx (blocks 500..531) ----------
template<bool PS>
__global__ void __launch_bounds__(256) score_attn(
    const float* __restrict__ linW,
    const unsigned short* __restrict__ Whi, const unsigned short* __restrict__ Wlo,
    const float* __restrict__ linb,
    const unsigned short* __restrict__ Xlhi_r, const unsigned short* __restrict__ Xllo_r,
    unsigned short* __restrict__ Xlhi_w, unsigned short* __restrict__ Xllo_w,
    unsigned short* __restrict__ Xghi_w, unsigned short* __restrict__ Xglo_w,
    const float* __restrict__ h_t, const float* __restrict__ energies,
    const float* __restrict__ enc,
    float* __restrict__ out, float* __restrict__ Pm, float* __restrict__ Ps,
    int* __restrict__ Pa, int t)
{
    __shared__ float Lm[4][32], Ls[4][32];
    __shared__ int   La[4][32];
    __shared__ float hrow[512], aw[128], red[256];
    int tid = threadIdx.x;
    if (blockIdx.x < 500) {
        int wave = tid >> 6, lane = tid & 63;
        int c = lane & 15, grp = lane >> 4, kg = grp * 8;
        int col = blockIdx.x * 64 + wave * 16 + c;
        const unsigned short* x0h = Xlhi_r + (size_t)c * KLIN + kg;
        const unsigned short* x0l = Xllo_r + (size_t)c * KLIN + kg;
        f32x4 acc0 = {0.f,0.f,0.f,0.f}, acc1 = {0.f,0.f,0.f,0.f};
        #pragma unroll 2
        for (int k0 = 0; k0 < 1024; k0 += 32) {
            bf16x8 bh, bl;
            if (PS) {
                bh = *(const bf16x8*)(Whi + (size_t)col * 1024 + k0 + kg);
                bl = *(const bf16x8*)(Wlo + (size_t)col * 1024 + k0 + kg);
            } else {
                split8(linW + (size_t)col * 1024 + k0 + kg, bh, bl);
            }
            bf16x8 a0h = *(const bf16x8*)(x0h + k0);
            bf16x8 a0l = *(const bf16x8*)(x0l + k0);
            bf16x8 a1h = *(const bf16x8*)(x0h + 16 * KLIN + k0);
            bf16x8 a1l = *(const bf16x8*)(x0l + 16 * KLIN + k0);
            acc0 = __builtin_amdgcn_mfma_f32_16x16x32_bf16(a0h, bh, acc0, 0, 0, 0);
            acc1 = __builtin_amdgcn_mfma_f32_16x16x32_bf16(a1h, bh, acc1, 0, 0, 0);
            acc0 = __builtin_amdgcn_mfma_f32_16x16x32_bf16(a0l, bh, acc0, 0, 0, 0);
            acc1 = __builtin_amdgcn_mfma_f32_16x16x32_bf16(a1l, bh, acc1, 0, 0, 0);
            acc0 = __builtin_amdgcn_mfma_f32_16x16x32_bf16(a0h, bl, acc0, 0, 0, 0);
            acc1 = __builtin_amdgcn_mfma_f32_16x16x32_bf16(a1h, bl, acc1, 0, 0, 0);
        }
        float bias = linb[col];
        float v[8];
        int r0 = grp * 4;
        #pragma unroll
        for (int i = 0; i < 4; ++i) {
            v[i]     = acc0[i] + bias;
            v[i + 4] = acc1[i] + bias;
            out[(size_t)((r0 + i) * L + t) * V + col]      = v[i];
            out[(size_t)((r0 + i + 16) * L + t) * V + col] = v[i + 4];
        }
        // per-row partials over this block's 64 cols: first 16-lane groups, then 4 waves
        #pragma unroll
        for (int i = 0; i < 8; ++i) {
            float m = v[i]; int mc = col;
            #pragma unroll
            for (int d = 1; d < 16; d <<= 1) {
                float om = __shfl_xor(m, d); int oc = __shfl_xor(mc, d);
                if (om > m || (om == m && oc < mc)) { m = om; mc = oc; }
            }
            float s = expf(v[i] - m);
            #pragma unroll
            for (int d = 1; d < 16; d <<= 1) s += __shfl_xor(s, d);
            if (c == 0) {
                int row = (i < 4) ? r0 + i : r0 + (i - 4) + 16;
                Lm[wave][row] = m; La[wave][row] = mc; Ls[wave][row] = s;
            }
        }
        __syncthreads();
        if (tid < 32) {
            float M = Lm[0][tid]; int a = La[0][tid];
            #pragma unroll
            for (int q = 1; q < 4; ++q) {
                float om = Lm[q][tid]; int oa = La[q][tid];
                if (om > M || (om == M && oa < a)) { M = om; a = oa; }
            }
            float S = 0.f;
            #pragma unroll
            for (int q = 0; q < 4; ++q) S += Ls[q][tid] * expf(Lm[q][tid] - M);
            Pm[tid * 500 + blockIdx.x] = M;
            Pa[tid * 500 + blockIdx.x] = a;
            Ps[tid * 500 + blockIdx.x] = S;
        }
    } else {
        // attention path: b = blockIdx.x - 500; uses h(t), writes ctx(t+1)
        int b = blockIdx.x - 500;
        for (int j = tid; j < 512; j += 256) hrow[j] = h_t[(size_t)j * 32 + b];
        __syncthreads();
        {
            int tt = tid >> 1, half = tid & 1;
            const float4* e4 = (const float4*)(energies + ((size_t)(b * T + tt)) * 512 + half * 256);
            const float4* h4 = (const float4*)(hrow + half * 256);
            float p = 0.f;
            #pragma unroll 4
            for (int k = 0; k < 64; ++k) {
                float4 a = e4[k], cc = h4[k];
                p += a.x * cc.x + a.y * cc.y + a.z * cc.z + a.w * cc.w;
            }
            p += __shfl_xor(p, 1);
            if (half == 0) aw[tt] = p;
        }
        __syncthreads();
        red[tid] = (tid < 128) ? aw[tid] : -INFINITY; __syncthreads();
        for (int s = 128; s > 0; s >>= 1) { if (tid < s) red[tid] = fmaxf(red[tid], red[tid + s]); __syncthreads(); }
        float am = red[0];
        __syncthreads();
        if (tid < 128) { float e = expf(aw[tid] - am); aw[tid] = e; red[tid] = e; } else red[tid] = 0.f;
        __syncthreads();
        for (int s = 128; s > 0; s >>= 1) { if (tid < s) red[tid] += red[tid + s]; __syncthreads(); }
        float asum = red[0];
        __syncthreads();
        float c0 = 0.f, c1 = 0.f;
        for (int tt2 = 0; tt2 < T; ++tt2) {
            float a = aw[tt2];
            const float* er = enc + ((size_t)(b * T + tt2)) * 512;
            c0 += a * er[tid];
            c1 += a * er[tid + 256];
        }
        c0 /= asum; c1 /= asum;
        split1(c0, &Xlhi_w[(size_t)b * KLIN + 512 + tid],       &Xllo_w[(size_t)b * KLIN + 512 + tid]);
        split1(c1, &Xlhi_w[(size_t)b * KLIN + 512 + tid + 256], &Xllo_w[(size_t)b * KLIN + 512 + tid + 256]);
        split1(c0, &Xghi_w[(size_t)b * KGRU + 512 + tid],       &Xglo_w[(size_t)b * KGRU + 512 + tid]);
        split1(c1, &Xghi_w[(size_t)b * KGRU + 512 + tid + 256], &Xglo_w[(size_t)b * KGRU + 512 + tid + 256]);
    }
}

// ---------- finalize: reduce 500 partials -> lse, argmax; emb gather ----------
__global__ void __launch_bounds__(256) finalize(
    const float* __restrict__ Pm, const float* __restrict__ Ps, const int* __restrict__ Pa,
    const float* __restrict__ emb,
    unsigned short* __restrict__ Xghi_w, unsigned short* __restrict__ Xglo_w,
    float* __restrict__ lse_buf, int t)
{
    __shared__ float sm[256]; __shared__ int sa[256]; __shared__ float ss[256];
    int b = blockIdx.x, tid = threadIdx.x;
    float m1 = -INFINITY, s1 = 0.f; int a1 = 0x7fffffff;
    float m2 = -INFINITY, s2 = 0.f; int a2 = 0x7fffffff;
    if (tid < 500)       { m1 = Pm[b * 500 + tid];       a1 = Pa[b * 500 + tid];       s1 = Ps[b * 500 + tid]; }
    if (tid + 256 < 500) { m2 = Pm[b * 500 + tid + 256]; a2 = Pa[b * 500 + tid + 256]; s2 = Ps[b * 500 + tid + 256]; }
    float m = m1; int a = a1;
    if (m2 > m || (m2 == m && a2 < a)) { m = m2; a = a2; }
    sm[tid] = m; sa[tid] = a; __syncthreads();
    for (int s = 128; s > 0; s >>= 1) {
        if (tid < s) {
            float om = sm[tid + s]; int oa = sa[tid + s];
            if (om > sm[tid] || (om == sm[tid] && oa < sa[tid])) { sm[tid] = om; sa[tid] = oa; }
        }
        __syncthreads();
    }
    float M = sm[0]; int amax = sa[0];
    __syncthreads();
    float sc = s1 * expf(m1 - M) + s2 * expf(m2 - M);
    ss[tid] = sc; __syncthreads();
    for (int s = 128; s > 0; s >>= 1) { if (tid < s) ss[tid] += ss[tid + s]; __syncthreads(); }
    if (tid == 0) lse_buf[b * L + t] = M + logf(ss[0]);
    for (int j = tid; j < 512; j += 256)
        split1(emb[(size_t)amax * D + j], &Xghi_w[(size_t)b * KGRU + j], &Xglo_w[(size_t)b * KGRU + j]);
}

// ---------- final: out -= lse (one pass over all 48 steps) ----------
__global__ void __launch_bounds__(256) subtract_lse(float* __restrict__ out,
                                                    const float* __restrict__ lse_buf)
{
    long i4 = (long)blockIdx.x * 256 + threadIdx.x;     // float4 index; 8000 per row
    int row = (int)(i4 / 8000);                         // row = b*L + t (matches lse layout)
    float l = lse_buf[row];
    float4* p = (float4*)out + i4;
    float4 v = *p;
    v.x -= l; v.y -= l; v.z -= l; v.w -= l;
    *p = v;
}

extern "C" void kernel_launch(void* const* d_in, const int* in_sizes, int n_in,
                              void* d_out, int out_size, void* d_ws, size_t ws_size,
                              hipStream_t stream) {
    const int*   inputs  = (const int*)d_in[0];
    const float* context = (const float*)d_in[1];
    const float* enc     = (const float*)d_in[3];
    const float* emb     = (const float*)d_in[4];
    const float* Wih     = (const float*)d_in[5];
    const float* Whh     = (const float*)d_in[6];
    const float* bih     = (const float*)d_in[7];
    const float* bhh     = (const float*)d_in[8];
    const float* linW    = (const float*)d_in[9];
    const float* linb    = (const float*)d_in[10];
    const float* attnW   = (const float*)d_in[11];
    const float* attnb   = (const float*)d_in[12];
    float* out = (float*)d_out;

    // workspace layout
    char* w = (char*)d_ws;
    unsigned short* Ghi = (unsigned short*)w; w += (size_t)1536 * KGRU * 2;   // 4.72 MB
    unsigned short* Glo = (unsigned short*)w; w += (size_t)1536 * KGRU * 2;
    float* energies = (float*)w;              w += (size_t)B * T * 512 * 4;   // 8.39 MB
    float* h_t      = (float*)w;              w += (size_t)H * B * 4;
    unsigned short* Xghi[2]; unsigned short* Xglo[2];
    unsigned short* Xlhi[2]; unsigned short* Xllo[2];
    for (int q = 0; q < 2; ++q) {
        Xghi[q] = (unsigned short*)w; w += (size_t)B * KGRU * 2;
        Xglo[q] = (unsigned short*)w; w += (size_t)B * KGRU * 2;
        Xlhi[q] = (unsigned short*)w; w += (size_t)B * KLIN * 2;
        Xllo[q] = (unsigned short*)w; w += (size_t)B * KLIN * 2;
    }
    float* Pm = (float*)w; w += (size_t)32 * 500 * 4;
    float* Ps = (float*)w; w += (size_t)32 * 500 * 4;
    int*   Pa = (int*)w;   w += (size_t)32 * 500 * 4;
    float* lse_buf = (float*)w; w += (size_t)B * L * 4;
    size_t base_need = (size_t)(w - (char*)d_ws);
    unsigned short* Whi = (unsigned short*)w; w += (size_t)V * KLIN * 2;      // 65.5 MB
    unsigned short* Wlo = (unsigned short*)w; w += (size_t)V * KLIN * 2;
    bool pres = ws_size >= base_need + (size_t)V * KLIN * 4;

    if (pres)
        presplit_lin<<<16000, 256, 0, stream>>>(linW, Whi, Wlo);
    presplit_gru<<<1152, 256, 0, stream>>>(Wih, Whh, Ghi, Glo);
    init_state<<<64, 256, 0, stream>>>(inputs, context, emb, h_t, Xghi[0], Xglo[0], Xlhi[0], Xllo[0]);
    energies_gemm<<<dim3(128, 8), 256, 0, stream>>>(enc, attnW, attnb, energies);

    for (int t = 0; t < L; ++t) {
        int r = t & 1, n = (t + 1) & 1;
        gru_fused<<<32, 384, 0, stream>>>(Ghi, Glo, Xghi[r], Xglo[r],
                                          Xghi[n], Xglo[n], Xlhi[r], Xllo[r],
                                          bih, bhh, h_t);
        if (pres)
            score_attn<true><<<532, 256, 0, stream>>>(linW, Whi, Wlo, linb,
                Xlhi[r], Xllo[r], Xlhi[n], Xllo[n], Xghi[n], Xglo[n],
                h_t, energies, enc, out, Pm, Ps, Pa, t);
        else
            score_attn<false><<<532, 256, 0, stream>>>(linW, Whi, Wlo, linb,
                Xlhi[r], Xllo[r], Xlhi[n], Xllo[n], Xghi[n], Xglo[n],
                h_t, energies, enc, out, Pm, Ps, Pa, t);
        finalize<<<32, 256, 0, stream>>>(Pm, Ps, Pa, emb, Xghi[n], Xglo[n], lse_buf, t);
    }
    subtract_lse<<<48000, 256, 0, stream>>>(out, lse_buf);
}